// Round 6
// baseline (102.370 us; speedup 1.0000x reference)
//
#include <hip/hip_runtime.h>
#include <math.h>

#define N_SAMPLES 131072
#define HIDDEN 1024
#define SEGS 4
#define SEG_UNITS (HIDDEN / SEGS)        // 256
#define PAIRS 128                        // sample-pairs per block
#define SAMPLES_PER_BLOCK (2 * PAIRS)    // 256
#define EVAL_THREADS (SEGS * PAIRS)      // 512

typedef float v2f __attribute__((ext_vector_type(2)));

__device__ __forceinline__ float softplusf(float v) {
    return fmaxf(v, 0.0f) + log1pf(expf(-fabsf(v)));
}
__device__ __forceinline__ float kl_term_f(float mu, float sigma, float inv_prior) {
    float r = sigma * inv_prior;
    float m = mu * inv_prior;
    return 0.5f * (-2.0f * logf(r) - 1.0f + r * r + m * m);
}

// ---------------------------------------------------------------------------
// Kernel 1: parallel prep. Blocks 0-3: sample params for 256 units each.
// Block 4: KL scalar. params[j] = {w1,b1,w2a,w2b}; params[HIDDEN] = {b2a,b2b,0,0}
// Real exec ~1 us; its 41 us rocprof dur is the d_ws poison-fill drain (WAW).
// ---------------------------------------------------------------------------
__global__ __launch_bounds__(256) void bbb_prep(
    const float* __restrict__ W1_mu, const float* __restrict__ W1_rho,
    const float* __restrict__ b1_mu, const float* __restrict__ b1_rho,
    const float* __restrict__ W2_mu, const float* __restrict__ W2_rho,
    const float* __restrict__ b2_mu, const float* __restrict__ b2_rho,
    const float* __restrict__ eps_W1, const float* __restrict__ eps_b1,
    const float* __restrict__ eps_W2, const float* __restrict__ eps_b2,
    float4* __restrict__ params,   // [HIDDEN+1]
    float* __restrict__ kl_out)    // scalar
{
    const int tid = threadIdx.x;
    const int b   = blockIdx.x;

    if (b < 4) {
        const int u = b * 256 + tid;
        float w1  = fmaf(softplusf(W1_rho[u]), eps_W1[u], W1_mu[u]);
        float bb1 = fmaf(softplusf(b1_rho[u]), eps_b1[u], b1_mu[u]);
        float w2a = fmaf(softplusf(W2_rho[u]),          eps_W2[u],          W2_mu[u]);
        float w2b = fmaf(softplusf(W2_rho[HIDDEN + u]), eps_W2[HIDDEN + u], W2_mu[HIDDEN + u]);
        params[u] = make_float4(w1, bb1, w2a, w2b);
        if (b == 0 && tid == 0) {
            float bb2a = fmaf(softplusf(b2_rho[0]), eps_b2[0], b2_mu[0]);
            float bb2b = fmaf(softplusf(b2_rho[1]), eps_b2[1], b2_mu[1]);
            params[HIDDEN] = make_float4(bb2a, bb2b, 0.0f, 0.0f);
        }
    } else {
        __shared__ double s_part[4];
        const float ip1 = 0.25f;          // 1 / 4.0
        const float ip2 = 32.0f / 2.25f;  // 1 / (2.25/32)

        double kl = 0.0;
        #pragma unroll
        for (int k = 0; k < 4; ++k) {
            const int u = tid + 256 * k;
            kl += (double)kl_term_f(W1_mu[u], softplusf(W1_rho[u]), ip1);
            kl += (double)kl_term_f(b1_mu[u], softplusf(b1_rho[u]), ip1);
            kl += (double)kl_term_f(W2_mu[u],          softplusf(W2_rho[u]),          ip2);
            kl += (double)kl_term_f(W2_mu[HIDDEN + u], softplusf(W2_rho[HIDDEN + u]), ip2);
        }
        if (tid < 2) {
            kl += (double)kl_term_f(b2_mu[tid], softplusf(b2_rho[tid]), ip2);
        }
        #pragma unroll
        for (int off = 32; off > 0; off >>= 1) kl += __shfl_down(kl, off, 64);
        if ((tid & 63) == 0) s_part[tid >> 6] = kl;
        __syncthreads();
        if (tid == 0) {
            *kl_out = (float)(s_part[0] + s_part[1] + s_part[2] + s_part[3]);
        }
    }
}

// ---------------------------------------------------------------------------
// Kernel 2: dense eval, split-4 over units, 2 samples per thread (packed f32).
// params address wave-uniform -> s_load through scalar cache (broadcast).
// 512 blocks x 512 threads -> 4 blocks/CU -> 32 waves/CU. Inner loop 256
// iters, unroll 16 for s_load_dwordx16 batching; 4-way LDS partial combine.
// ---------------------------------------------------------------------------
__global__ __launch_bounds__(EVAL_THREADS) void bbb_eval(
    const float* __restrict__ x,
    const float4* __restrict__ params,
    float* __restrict__ means,
    float* __restrict__ stds)
{
    __shared__ float4 s_part[SEGS][PAIRS];

    const int tid  = threadIdx.x;
    const int pair = tid & (PAIRS - 1);
    const int seg  = __builtin_amdgcn_readfirstlane(tid >> 7);  // wave-uniform
    const int base = blockIdx.x * SAMPLES_PER_BLOCK;

    const v2f xv = *(const v2f*)(x + base + 2 * pair);

    const float4* __restrict__ p = params + seg * SEG_UNITS;

    v2f aa = {0.0f, 0.0f};
    v2f ab = {0.0f, 0.0f};
    #pragma unroll 16
    for (int j = 0; j < SEG_UNITS; ++j) {
        float4 q = p[j];                     // wave-uniform -> s_load
        v2f h = __builtin_elementwise_fma((v2f)q.x, xv, (v2f)q.y);
        h = __builtin_elementwise_max(h, (v2f)0.0f);
        aa = __builtin_elementwise_fma(h, (v2f)q.z, aa);
        ab = __builtin_elementwise_fma(h, (v2f)q.w, ab);
    }
    s_part[seg][pair] = make_float4(aa.x, aa.y, ab.x, ab.y);
    __syncthreads();

    if (tid < PAIRS) {
        const float4 b2 = params[HIDDEN];
        float4 acc = s_part[0][tid];
        #pragma unroll
        for (int s = 1; s < SEGS; ++s) {
            float4 v = s_part[s][tid];
            acc.x += v.x; acc.y += v.y; acc.z += v.z; acc.w += v.w;
        }
        float m0 = acc.x + b2.x;
        float m1 = acc.y + b2.x;
        float u0 = acc.z + b2.y;
        float u1 = acc.w + b2.y;
        *(float2*)(means + base + 2 * tid) = make_float2(m0, m1);
        *(float2*)(stds  + base + 2 * tid) =
            make_float2(1e-5f + softplusf(u0), 1e-5f + softplusf(u1));
    }
}

extern "C" void kernel_launch(void* const* d_in, const int* in_sizes, int n_in,
                              void* d_out, int out_size, void* d_ws, size_t ws_size,
                              hipStream_t stream) {
    const float* x      = (const float*)d_in[0];
    const float* W1_mu  = (const float*)d_in[1];
    const float* W1_rho = (const float*)d_in[2];
    const float* b1_mu  = (const float*)d_in[3];
    const float* b1_rho = (const float*)d_in[4];
    const float* W2_mu  = (const float*)d_in[5];
    const float* W2_rho = (const float*)d_in[6];
    const float* b2_mu  = (const float*)d_in[7];
    const float* b2_rho = (const float*)d_in[8];
    const float* eps_W1 = (const float*)d_in[9];
    const float* eps_b1 = (const float*)d_in[10];
    const float* eps_W2 = (const float*)d_in[11];
    const float* eps_b2 = (const float*)d_in[12];

    float* out = (float*)d_out;
    float4* params_ws = (float4*)d_ws;   // (HIDDEN+1) float4 = 16.4 KB

    bbb_prep<<<5, 256, 0, stream>>>(
        W1_mu, W1_rho, b1_mu, b1_rho, W2_mu, W2_rho, b2_mu, b2_rho,
        eps_W1, eps_b1, eps_W2, eps_b2,
        params_ws, out + 2 * N_SAMPLES);

    bbb_eval<<<N_SAMPLES / SAMPLES_PER_BLOCK, EVAL_THREADS, 0, stream>>>(
        x, params_ws, out, out + N_SAMPLES);
}

// Round 7
// 94.792 us; speedup vs baseline: 1.0799x; 1.0799x over previous
//
#include <hip/hip_runtime.h>
#include <math.h>

#define N_SAMPLES 131072
#define HIDDEN 1024
#define SEGS 8
#define SEG_UNITS (HIDDEN / SEGS)        // 128
#define PAIRS 128                        // sample-pairs per block
#define SAMPLES_PER_BLOCK (2 * PAIRS)    // 256

typedef float v2f __attribute__((ext_vector_type(2)));

__device__ __forceinline__ float softplusf(float v) {
    return fmaxf(v, 0.0f) + log1pf(expf(-fabsf(v)));
}
__device__ __forceinline__ float kl_term_f(float mu, float sigma, float inv_prior) {
    float r = sigma * inv_prior;
    float m = mu * inv_prior;
    return 0.5f * (-2.0f * logf(r) - 1.0f + r * r + m * m);
}

// ---------------------------------------------------------------------------
// Kernel 1: sample weights (float), KL (float terms, double accumulation).
// One block, 1024 threads. params[j] = {w1, b1, w2a, w2b}; params[HIDDEN] = {b2a, b2b,0,0}
// (round-3 configuration: best measured total, 95.5 us)
// ---------------------------------------------------------------------------
__global__ __launch_bounds__(1024) void bbb_prep(
    const float* __restrict__ W1_mu, const float* __restrict__ W1_rho,
    const float* __restrict__ b1_mu, const float* __restrict__ b1_rho,
    const float* __restrict__ W2_mu, const float* __restrict__ W2_rho,
    const float* __restrict__ b2_mu, const float* __restrict__ b2_rho,
    const float* __restrict__ eps_W1, const float* __restrict__ eps_b1,
    const float* __restrict__ eps_W2, const float* __restrict__ eps_b2,
    float4* __restrict__ params,   // [HIDDEN+1]
    float* __restrict__ kl_out)    // scalar
{
    __shared__ double s_part[16];
    const int tid = threadIdx.x;

    const float ip1 = 0.25f;          // 1 / (4.0/sqrt(1))
    const float ip2 = 32.0f / 2.25f;  // 1 / (2.25/sqrt(1024))

    float w1mu  = W1_mu[tid],          w1rho  = W1_rho[tid];
    float b1mu  = b1_mu[tid],          b1rho  = b1_rho[tid];
    float w2amu = W2_mu[tid],          w2arho = W2_rho[tid];
    float w2bmu = W2_mu[HIDDEN + tid], w2brho = W2_rho[HIDDEN + tid];

    float sg_w1  = softplusf(w1rho);
    float sg_b1  = softplusf(b1rho);
    float sg_w2a = softplusf(w2arho);
    float sg_w2b = softplusf(w2brho);

    float w1  = fmaf(sg_w1,  eps_W1[tid],          w1mu);
    float bb1 = fmaf(sg_b1,  eps_b1[tid],          b1mu);
    float w2a = fmaf(sg_w2a, eps_W2[tid],          w2amu);
    float w2b = fmaf(sg_w2b, eps_W2[HIDDEN + tid], w2bmu);

    params[tid] = make_float4(w1, bb1, w2a, w2b);

    double kl = (double)kl_term_f(w1mu,  sg_w1,  ip1)
              + (double)kl_term_f(b1mu,  sg_b1,  ip1)
              + (double)kl_term_f(w2amu, sg_w2a, ip2)
              + (double)kl_term_f(w2bmu, sg_w2b, ip2);

    if (tid < 2) {
        kl += (double)kl_term_f(b2_mu[tid], softplusf(b2_rho[tid]), ip2);
    }
    if (tid == 0) {
        float bb2a = fmaf(softplusf(b2_rho[0]), eps_b2[0], b2_mu[0]);
        float bb2b = fmaf(softplusf(b2_rho[1]), eps_b2[1], b2_mu[1]);
        params[HIDDEN] = make_float4(bb2a, bb2b, 0.0f, 0.0f);
    }

    #pragma unroll
    for (int off = 32; off > 0; off >>= 1) kl += __shfl_down(kl, off, 64);
    if ((tid & 63) == 0) s_part[tid >> 6] = kl;
    __syncthreads();
    if (tid == 0) {
        double t = 0.0;
        #pragma unroll
        for (int i = 0; i < 16; ++i) t += s_part[i];
        *kl_out = (float)t;
    }
}

// ---------------------------------------------------------------------------
// Kernel 2: dense eval, split-8 over units, 2 samples per thread (packed f32).
// params address is wave-uniform -> s_load through scalar cache (broadcast).
// 512 blocks x 1024 threads -> 2 blocks/CU -> 32 waves/CU.
// ---------------------------------------------------------------------------
__global__ __launch_bounds__(1024) void bbb_eval(
    const float* __restrict__ x,
    const float4* __restrict__ params,
    float* __restrict__ means,
    float* __restrict__ stds)
{
    __shared__ float4 s_part[SEGS][PAIRS];

    const int tid  = threadIdx.x;
    const int pair = tid & (PAIRS - 1);
    const int seg  = __builtin_amdgcn_readfirstlane(tid >> 7);  // wave-uniform
    const int base = blockIdx.x * SAMPLES_PER_BLOCK;

    const v2f xv = *(const v2f*)(x + base + 2 * pair);

    const float4* __restrict__ p = params + seg * SEG_UNITS;

    v2f aa = {0.0f, 0.0f};
    v2f ab = {0.0f, 0.0f};
    #pragma unroll 8
    for (int j = 0; j < SEG_UNITS; ++j) {
        float4 q = p[j];                     // wave-uniform -> s_load
        v2f h = __builtin_elementwise_fma((v2f)q.x, xv, (v2f)q.y);
        h = __builtin_elementwise_max(h, (v2f)0.0f);
        aa = __builtin_elementwise_fma(h, (v2f)q.z, aa);
        ab = __builtin_elementwise_fma(h, (v2f)q.w, ab);
    }
    s_part[seg][pair] = make_float4(aa.x, aa.y, ab.x, ab.y);
    __syncthreads();

    if (tid < PAIRS) {
        const float4 b2 = params[HIDDEN];
        float4 acc = s_part[0][tid];
        #pragma unroll
        for (int s = 1; s < SEGS; ++s) {
            float4 v = s_part[s][tid];
            acc.x += v.x; acc.y += v.y; acc.z += v.z; acc.w += v.w;
        }
        float m0 = acc.x + b2.x;
        float m1 = acc.y + b2.x;
        float u0 = acc.z + b2.y;
        float u1 = acc.w + b2.y;
        *(float2*)(means + base + 2 * tid) = make_float2(m0, m1);
        *(float2*)(stds  + base + 2 * tid) =
            make_float2(1e-5f + softplusf(u0), 1e-5f + softplusf(u1));
    }
}

extern "C" void kernel_launch(void* const* d_in, const int* in_sizes, int n_in,
                              void* d_out, int out_size, void* d_ws, size_t ws_size,
                              hipStream_t stream) {
    const float* x      = (const float*)d_in[0];
    const float* W1_mu  = (const float*)d_in[1];
    const float* W1_rho = (const float*)d_in[2];
    const float* b1_mu  = (const float*)d_in[3];
    const float* b1_rho = (const float*)d_in[4];
    const float* W2_mu  = (const float*)d_in[5];
    const float* W2_rho = (const float*)d_in[6];
    const float* b2_mu  = (const float*)d_in[7];
    const float* b2_rho = (const float*)d_in[8];
    const float* eps_W1 = (const float*)d_in[9];
    const float* eps_b1 = (const float*)d_in[10];
    const float* eps_W2 = (const float*)d_in[11];
    const float* eps_b2 = (const float*)d_in[12];

    float* out = (float*)d_out;
    float4* params_ws = (float4*)d_ws;   // (HIDDEN+1) float4 = 16.4 KB

    bbb_prep<<<1, HIDDEN, 0, stream>>>(
        W1_mu, W1_rho, b1_mu, b1_rho, W2_mu, W2_rho, b2_mu, b2_rho,
        eps_W1, eps_b1, eps_W2, eps_b2,
        params_ws, out + 2 * N_SAMPLES);

    bbb_eval<<<N_SAMPLES / SAMPLES_PER_BLOCK, 1024, 0, stream>>>(
        x, params_ws, out, out + N_SAMPLES);
}